// Round 12
// baseline (288.463 us; speedup 1.0000x reference)
//
#include <hip/hip_runtime.h>
#include <hip/hip_fp16.h>

// GCN 2-layer, CSR-gather, fp16 storage / fp32 math, MFMA GEMMs. R12.
// R11 confirmed the serial-bubble model (pipelined gather: 90->85us, 2.33->
// 2.84 TB/s). Non-fused tail = ~200us. R12 attacks its two structural sinks:
//  (a) k_gath2 was per-node-overhead-bound (z rows 128B -> ~3 loads/node vs
//      full header+butterfly+store cost): now TWO nodes per wave (half-wave
//      per node, 4 slots x 8 lanes), 16-deep fast path; butterfly/shfl stay
//      within each 32-lane half (divergence-safe, per-half uniform d).
//  (b) binning kernels ran at 1 block/CU: NBLK 256->800 (EPB=2000), scanT
//      restructured to 4 rows/thread.
//   k_histwt : edge histogram (800 blks) || weight transpose (96 blks)
//   k_scanT  : column scan (800 rows, 4/thread) -> startOff, btot
//   k_scatB  : redundant LDS scan of btot + edge scatter (blk0 publishes)
//   k_fillb  : deg/rowptr/dinv + srcIdx + y=half(x*dinv)
//   k_fused  : R11 pipelined gather + GEMM1(relu,b1)+GEMM2(*dinv) [UNCHANGED]
//   k_gath2  : layer-2 gather, 2 nodes/wave -> out
// 6 dispatches, no global atomics, no device barriers.

constexpr int NN = 100000;
constexpr int NE = 1600000;
constexpr int BSH = 7;
constexpr int NB = (NN + 127) >> BSH;   // 782
constexpr int NBLK = 800;               // binning blocks (3.1/CU)
constexpr int EPB = NE / NBLK;          // 2000 (exact)
constexpr int TSTR = 784;

typedef _Float16 f16x8 __attribute__((ext_vector_type(8)));
typedef float f32x4 __attribute__((ext_vector_type(4)));

// ---- histogram (blocks 0..NBLK-1) + weight transpose (NBLK..NBLK+95) ----
__global__ __launch_bounds__(256) void k_histwt(const int* __restrict__ cols,
                                                int* __restrict__ table,
                                                const float* __restrict__ W1,
                                                const float* __restrict__ W2,
                                                __half* __restrict__ Wt1,
                                                __half* __restrict__ Wt2) {
  if (blockIdx.x < NBLK) {
    __shared__ int cnt[NB];
    for (int i = threadIdx.x; i < NB; i += 256) cnt[i] = 0;
    __syncthreads();
    int base = blockIdx.x * EPB;
    for (int i = threadIdx.x; i < EPB; i += 256)
      atomicAdd(&cnt[cols[base + i] >> BSH], 1);
    __syncthreads();
    for (int i = threadIdx.x; i < NB; i += 256)
      table[blockIdx.x * TSTR + i] = cnt[i];
  } else {
    int i = (blockIdx.x - NBLK) * 256 + threadIdx.x;  // 24576 = 16384 + 8192
    if (i < 16384) {
      int k = i >> 7, n = i & 127;
      Wt1[n * 128 + k] = __float2half(W1[i]);
    } else {
      int j = i - 16384;
      int k = j >> 6, n = j & 63;
      Wt2[n * 128 + k] = __float2half(W2[j]);
    }
  }
}

// -- scan table columns over the NBLK block-histograms: 4 rows per thread ----
__global__ __launch_bounds__(256) void k_scanT(const int* __restrict__ table,
                                               int* __restrict__ startOff,
                                               int* __restrict__ btot) {
  __shared__ int s[256];
  int b = blockIdx.x, t = threadIdx.x;
  int r0 = t * 4;
  int v0 = (r0 + 0 < NBLK) ? table[(size_t)(r0 + 0) * TSTR + b] : 0;
  int v1 = (r0 + 1 < NBLK) ? table[(size_t)(r0 + 1) * TSTR + b] : 0;
  int v2 = (r0 + 2 < NBLK) ? table[(size_t)(r0 + 2) * TSTR + b] : 0;
  int v3 = (r0 + 3 < NBLK) ? table[(size_t)(r0 + 3) * TSTR + b] : 0;
  int tsum = v0 + v1 + v2 + v3;
  s[t] = tsum;
  __syncthreads();
  for (int off = 1; off < 256; off <<= 1) {
    int tmp = (t >= off) ? s[t - off] : 0;
    __syncthreads();
    s[t] += tmp;
    __syncthreads();
  }
  int ex = s[t] - tsum;
  if (r0 + 0 < NBLK) startOff[(size_t)(r0 + 0) * TSTR + b] = ex;
  if (r0 + 1 < NBLK) startOff[(size_t)(r0 + 1) * TSTR + b] = ex + v0;
  if (r0 + 2 < NBLK) startOff[(size_t)(r0 + 2) * TSTR + b] = ex + v0 + v1;
  if (r0 + 3 < NBLK) startOff[(size_t)(r0 + 3) * TSTR + b] = ex + v0 + v1 + v2;
  if (t == 255) btot[b] = s[255];
}

// ---- per-block LDS scan of btot (redundant, proven) + edge scatter ----------
__global__ __launch_bounds__(256) void k_scatB(const int* __restrict__ rows,
                                               const int* __restrict__ cols,
                                               const int* __restrict__ startOff,
                                               const int* __restrict__ btot,
                                               int* __restrict__ bucketBase,
                                               unsigned* __restrict__ binned) {
  __shared__ int bb[NB];
  __shared__ int s[256];
  __shared__ int scnt[NB];
  int tid = threadIdx.x;
  int base4 = tid * 4;
  int d0 = (base4 + 0 < NB) ? btot[base4 + 0] : 0;
  int d1 = (base4 + 1 < NB) ? btot[base4 + 1] : 0;
  int d2 = (base4 + 2 < NB) ? btot[base4 + 2] : 0;
  int d3 = (base4 + 3 < NB) ? btot[base4 + 3] : 0;
  int tsum = d0 + d1 + d2 + d3;
  s[tid] = tsum;
  __syncthreads();
  for (int off = 1; off < 256; off <<= 1) {
    int tmp = (tid >= off) ? s[tid - off] : 0;
    __syncthreads();
    s[tid] += tmp;
    __syncthreads();
  }
  int ex = s[tid] - tsum;
  if (base4 + 0 < NB) bb[base4 + 0] = ex;
  if (base4 + 1 < NB) bb[base4 + 1] = ex + d0;
  if (base4 + 2 < NB) bb[base4 + 2] = ex + d0 + d1;
  if (base4 + 3 < NB) bb[base4 + 3] = ex + d0 + d1 + d2;
  __syncthreads();
  if (blockIdx.x == 0)
    for (int i = tid; i < NB; i += 256) bucketBase[i] = bb[i];
  for (int i = tid; i < NB; i += 256)
    scnt[i] = bb[i] + startOff[(size_t)blockIdx.x * TSTR + i];
  __syncthreads();
  int base = blockIdx.x * EPB;
  for (int i = tid; i < EPB; i += 256) {
    int c = cols[base + i];
    int r = rows[base + i];
    int pos = atomicAdd(&scnt[c >> BSH], 1);
    binned[pos] = ((unsigned)r << BSH) | (unsigned)(c & 127);
  }
}

// ------- per-bucket fill: deg/rowptr/dinv + node-grouped srcIdx + y ----------
__global__ __launch_bounds__(256) void k_fillb(const unsigned* __restrict__ binned,
                                               const int* __restrict__ bucketBase,
                                               const int* __restrict__ btot,
                                               int* __restrict__ rowptr,
                                               int* __restrict__ deg,
                                               float* __restrict__ dinv,
                                               int* __restrict__ srcIdx,
                                               const float4* __restrict__ x4,
                                               float2* __restrict__ y8) {
  __shared__ int cnt[128];
  __shared__ int sc[128];
  __shared__ int rp[128];
  __shared__ float sdv[128];
  int b = blockIdx.x;
  int nb0 = b << BSH;
  int nn = min(128, NN - nb0);
  int tid = threadIdx.x;
  if (tid < 128) cnt[tid] = 0;
  __syncthreads();
  int ebeg = bucketBase[b];
  int eend = ebeg + btot[b];
  for (int p = ebeg + tid; p < eend; p += 256)
    atomicAdd(&cnt[binned[p] & 127], 1);
  __syncthreads();
  int v = (tid < 128) ? cnt[tid] : 0;
  if (tid < 128) sc[tid] = v;
  __syncthreads();
  for (int off = 1; off < 128; off <<= 1) {
    int tmp = (tid < 128 && tid >= off) ? sc[tid - off] : 0;
    __syncthreads();
    if (tid < 128) sc[tid] += tmp;
    __syncthreads();
  }
  if (tid < 128) {
    int ex = sc[tid] - v;
    rp[tid] = ebeg + ex;
    float dv = rsqrtf((float)v + 1.0f);
    sdv[tid] = dv;
    if (tid < nn) {
      rowptr[nb0 + tid] = ebeg + ex;
      deg[nb0 + tid] = v;
      dinv[nb0 + tid] = dv;
    }
    cnt[tid] = 0;
  }
  __syncthreads();
  for (int p = ebeg + tid; p < eend; p += 256) {
    unsigned pk = binned[p];
    int cl = pk & 127;
    int local = atomicAdd(&cnt[cl], 1);
    srcIdx[rp[cl] + local] = (int)(pk >> BSH);
  }
  // fused k_y: this bucket's x rows -> y = half(x*dinv)
  int tot = nn << 5;
  const float4* xb = x4 + ((size_t)nb0 << 5);
  float2* yb = y8 + ((size_t)nb0 << 5);
  for (int i = tid; i < tot; i += 256) {
    float sfac = sdv[i >> 5];
    float4 vv = xb[i];
    union { __half2 h[2]; float2 f; } u;
    u.h[0] = __floats2half2_rn(vv.x * sfac, vv.y * sfac);
    u.h[1] = __floats2half2_rn(vv.z * sfac, vv.w * sfac);
    yb[i] = u.f;
  }
}

// ---- fused gather + GEMM1(+bias,relu) + GEMM2(+dinv), pipelined (R11) ------
__global__ __launch_bounds__(256, 8) void k_fused(
    const __half* __restrict__ y, const int* __restrict__ rowptr,
    const int* __restrict__ deg, const int* __restrict__ srcIdx,
    const float* __restrict__ dinv, const __half* __restrict__ Wt1,
    const float* __restrict__ b1, const __half* __restrict__ Wt2,
    __half* __restrict__ z) {
  __shared__ __align__(16) __half sA[16][136];
  __shared__ __align__(16) __half sB[16][136];
  const int w = threadIdx.x >> 6, l = threadIdx.x & 63;
  const int blk0 = blockIdx.x * 16;
  const int quad = l >> 4, m = l & 15;

  // header preload: lanes 0-3 hold deg/rowptr/dinv of the 4 nodes
  int hd = 0, hp = 0;
  float hv = 0.0f;
  if (l < 4) {
    hd = deg[blk0 + w * 4 + l];
    hp = rowptr[blk0 + w * 4 + l];
    hv = dinv[blk0 + w * 4 + l];
  }
  int d = __shfl(hd, 0);
  int ptr = __shfl(hp, 0);
  int my = (l < min(d, 64)) ? srcIdx[ptr + l] : 0;

  for (int i = 0; i < 4; ++i) {
    const int node = blk0 + w * 4 + i;
    const int dn = (i < 3) ? __shfl(hd, i + 1) : 0;
    const int pn = (i < 3) ? __shfl(hp, i + 1) : 0;
    int myn = (i < 3 && l < min(dn, 64)) ? srcIdx[pn + l] : 0;
    f16x8 sv = *reinterpret_cast<const f16x8*>(y + (size_t)node * 128 + m * 8);

    float acc[8];
#pragma unroll
    for (int j = 0; j < 8; j++) acc[j] = 0.0f;

    {
      int cnt = min(d, 64);
      int k = 0;
      for (; k + 16 <= cnt; k += 16) {
        int s0 = __shfl(my, k + quad);
        int s1 = __shfl(my, k + 4 + quad);
        int s2 = __shfl(my, k + 8 + quad);
        int s3 = __shfl(my, k + 12 + quad);
        f16x8 v0 = *reinterpret_cast<const f16x8*>(y + (size_t)s0 * 128 + m * 8);
        f16x8 v1 = *reinterpret_cast<const f16x8*>(y + (size_t)s1 * 128 + m * 8);
        f16x8 v2 = *reinterpret_cast<const f16x8*>(y + (size_t)s2 * 128 + m * 8);
        f16x8 v3 = *reinterpret_cast<const f16x8*>(y + (size_t)s3 * 128 + m * 8);
#pragma unroll
        for (int j = 0; j < 8; j++) acc[j] += (float)v0[j];
#pragma unroll
        for (int j = 0; j < 8; j++) acc[j] += (float)v1[j];
#pragma unroll
        for (int j = 0; j < 8; j++) acc[j] += (float)v2[j];
#pragma unroll
        for (int j = 0; j < 8; j++) acc[j] += (float)v3[j];
      }
      for (; k + 8 <= cnt; k += 8) {
        int s0 = __shfl(my, k + quad);
        int s1 = __shfl(my, k + 4 + quad);
        f16x8 v0 = *reinterpret_cast<const f16x8*>(y + (size_t)s0 * 128 + m * 8);
        f16x8 v1 = *reinterpret_cast<const f16x8*>(y + (size_t)s1 * 128 + m * 8);
#pragma unroll
        for (int j = 0; j < 8; j++) acc[j] += (float)v0[j];
#pragma unroll
        for (int j = 0; j < 8; j++) acc[j] += (float)v1[j];
      }
      for (; k < cnt; k += 4) {
        int idx = k + quad;
        bool valid = idx < cnt;
        int s0 = __shfl(my, valid ? idx : 0);
        f16x8 v0 = *reinterpret_cast<const f16x8*>(y + (size_t)s0 * 128 + m * 8);
        if (valid) {
#pragma unroll
          for (int j = 0; j < 8; j++) acc[j] += (float)v0[j];
        }
      }
    }
    for (int base = 64; base < d; base += 64) {  // rare tail d>64
      int cnt = min(64, d - base);
      int mt = (l < cnt) ? srcIdx[ptr + base + l] : 0;
      int k = 0;
      for (; k + 8 <= cnt; k += 8) {
        int s0 = __shfl(mt, k + quad);
        int s1 = __shfl(mt, k + 4 + quad);
        f16x8 v0 = *reinterpret_cast<const f16x8*>(y + (size_t)s0 * 128 + m * 8);
        f16x8 v1 = *reinterpret_cast<const f16x8*>(y + (size_t)s1 * 128 + m * 8);
#pragma unroll
        for (int j = 0; j < 8; j++) acc[j] += (float)v0[j];
#pragma unroll
        for (int j = 0; j < 8; j++) acc[j] += (float)v1[j];
      }
      for (; k < cnt; k += 4) {
        int idx = k + quad;
        bool valid = idx < cnt;
        int s0 = __shfl(mt, valid ? idx : 0);
        f16x8 v0 = *reinterpret_cast<const f16x8*>(y + (size_t)s0 * 128 + m * 8);
        if (valid) {
#pragma unroll
          for (int j = 0; j < 8; j++) acc[j] += (float)v0[j];
        }
      }
    }

#pragma unroll
    for (int j = 0; j < 8; j++) acc[j] += __shfl_xor(acc[j], 16);
#pragma unroll
    for (int j = 0; j < 8; j++) acc[j] += __shfl_xor(acc[j], 32);
    if (quad == 0) {
      float scn = __shfl(hv, i);
      f16x8 o;
#pragma unroll
      for (int j = 0; j < 8; j++)
        o[j] = (_Float16)((acc[j] + (float)sv[j]) * scn);
      *reinterpret_cast<f16x8*>(&sA[w * 4 + i][m * 8]) = o;
    }
    d = dn;
    ptr = pn;
    my = myn;
  }
  __syncthreads();

  // GEMM1: wave w -> col tiles 2w, 2w+1
  f16x8 afrag[4];
#pragma unroll
  for (int kk = 0; kk < 4; kk++)
    afrag[kk] = *reinterpret_cast<const f16x8*>(&sA[m][kk * 32 + quad * 8]);
  f32x4 acc1[2];
#pragma unroll
  for (int t = 0; t < 2; t++) {
    float bv = b1[(w * 2 + t) * 16 + m];
    acc1[t] = (f32x4){bv, bv, bv, bv};
  }
#pragma unroll
  for (int kk = 0; kk < 4; kk++) {
#pragma unroll
    for (int t = 0; t < 2; t++) {
      f16x8 b = *reinterpret_cast<const f16x8*>(
          Wt1 + (size_t)((w * 2 + t) * 16 + m) * 128 + kk * 32 + quad * 8);
      acc1[t] = __builtin_amdgcn_mfma_f32_16x16x32_f16(afrag[kk], b, acc1[t], 0, 0, 0);
    }
  }
#pragma unroll
  for (int t = 0; t < 2; t++)
#pragma unroll
    for (int i = 0; i < 4; i++)
      sB[quad * 4 + i][(w * 2 + t) * 16 + m] =
          __float2half(fmaxf(acc1[t][i], 0.0f));
  __syncthreads();

  // GEMM2: wave w -> col tile w
  f16x8 hfrag[4];
#pragma unroll
  for (int kk = 0; kk < 4; kk++)
    hfrag[kk] = *reinterpret_cast<const f16x8*>(&sB[m][kk * 32 + quad * 8]);
  f32x4 acc2 = (f32x4){0.f, 0.f, 0.f, 0.f};
#pragma unroll
  for (int kk = 0; kk < 4; kk++) {
    f16x8 b = *reinterpret_cast<const f16x8*>(
        Wt2 + (size_t)(w * 16 + m) * 128 + kk * 32 + quad * 8);
    acc2 = __builtin_amdgcn_mfma_f32_16x16x32_f16(hfrag[kk], b, acc2, 0, 0, 0);
  }
  float rs[4];
#pragma unroll
  for (int i = 0; i < 4; i++) rs[i] = dinv[blk0 + quad * 4 + i];
#pragma unroll
  for (int i = 0; i < 4; i++)
    sA[quad * 4 + i][w * 16 + m] = __float2half(acc2[i] * rs[i]);
  __syncthreads();

  if (threadIdx.x < 128) {
    int r = threadIdx.x >> 3, cc = threadIdx.x & 7;
    *reinterpret_cast<float4*>(z + (size_t)(blk0 + r) * 64 + cc * 8) =
        *reinterpret_cast<const float4*>(&sA[r][cc * 8]);
  }
}

// ---- layer-2 gather, TWO nodes per wave (half-wave per node) ----------------
// half h = lane>>5 owns node blockIdx*8 + wave*2 + h. Within a half: 4 slots
// (g) x 8 lanes (c) -> 4 rows per load instruction per node; 16-deep fast
// path covers Poisson(16) in one chunk. All shfl/butterfly stay inside the
// 32-lane half (uniform d per half -> lockstep within half; cross-half
// divergence is predication-safe).
__global__ __launch_bounds__(256) void k_gath2(const __half* __restrict__ z,
                                               const int* __restrict__ rowptr,
                                               const int* __restrict__ deg,
                                               const int* __restrict__ srcIdx,
                                               const float* __restrict__ dinv,
                                               const float* __restrict__ b2,
                                               float* __restrict__ out) {
  const int lane = threadIdx.x & 63;
  const int h = lane >> 5;       // node half 0/1
  const int l5 = lane & 31;
  const int g = l5 >> 3;         // slot 0..3
  const int c = l5 & 7;          // chunk: halfs [c*8, c*8+8)
  const int h32 = h << 5;
  int node = blockIdx.x * 8 + ((threadIdx.x >> 6) << 1) + h;
  if (node >= NN) return;
  int d = deg[node];             // uniform within half
  int p = rowptr[node];
  size_t coff = (size_t)c * 8;
  float acc[8];
#pragma unroll
  for (int i = 0; i < 8; i++) acc[i] = 0.0f;

  for (int base = 0; base < d; base += 32) {
    int cnt = min(32, d - base);
    int my = (l5 < cnt) ? srcIdx[p + base + l5] : 0;
    int k = 0;
    for (; k + 16 <= cnt; k += 16) {   // 16 neighbors, 4 loads in flight
      int s0 = __shfl(my, h32 + k + g);
      int s1 = __shfl(my, h32 + k + 4 + g);
      int s2 = __shfl(my, h32 + k + 8 + g);
      int s3 = __shfl(my, h32 + k + 12 + g);
      f16x8 v0 = *reinterpret_cast<const f16x8*>(z + (size_t)s0 * 64 + coff);
      f16x8 v1 = *reinterpret_cast<const f16x8*>(z + (size_t)s1 * 64 + coff);
      f16x8 v2 = *reinterpret_cast<const f16x8*>(z + (size_t)s2 * 64 + coff);
      f16x8 v3 = *reinterpret_cast<const f16x8*>(z + (size_t)s3 * 64 + coff);
#pragma unroll
      for (int i = 0; i < 8; i++) acc[i] += (float)v0[i];
#pragma unroll
      for (int i = 0; i < 8; i++) acc[i] += (float)v1[i];
#pragma unroll
      for (int i = 0; i < 8; i++) acc[i] += (float)v2[i];
#pragma unroll
      for (int i = 0; i < 8; i++) acc[i] += (float)v3[i];
    }
    for (; k + 8 <= cnt; k += 8) {     // 8 neighbors, 2 loads in flight
      int s0 = __shfl(my, h32 + k + g);
      int s1 = __shfl(my, h32 + k + 4 + g);
      f16x8 v0 = *reinterpret_cast<const f16x8*>(z + (size_t)s0 * 64 + coff);
      f16x8 v1 = *reinterpret_cast<const f16x8*>(z + (size_t)s1 * 64 + coff);
#pragma unroll
      for (int i = 0; i < 8; i++) acc[i] += (float)v0[i];
#pragma unroll
      for (int i = 0; i < 8; i++) acc[i] += (float)v1[i];
    }
    for (; k < cnt; k += 4) {          // remainder, predicated
      int idx = k + g;
      bool valid = idx < cnt;
      int s0 = __shfl(my, h32 + (valid ? idx : 0));
      f16x8 v0 = *reinterpret_cast<const f16x8*>(z + (size_t)s0 * 64 + coff);
      if (valid) {
#pragma unroll
        for (int i = 0; i < 8; i++) acc[i] += (float)v0[i];
      }
    }
  }
  // combine the 4 slots within this half (xor 8, 16 stay inside the half)
#pragma unroll
  for (int i = 0; i < 8; i++) acc[i] += __shfl_xor(acc[i], 8);
#pragma unroll
  for (int i = 0; i < 8; i++) acc[i] += __shfl_xor(acc[i], 16);
  if (g == 0) {
    f16x8 sv = *reinterpret_cast<const f16x8*>(z + (size_t)node * 64 + coff);
    float s = dinv[node];
    const float4* b4 = reinterpret_cast<const float4*>(b2);
    float4 bv0 = b4[2 * c], bv1 = b4[2 * c + 1];
    float4 o0, o1;
    o0.x = (acc[0] + (float)sv[0]) * s + bv0.x;
    o0.y = (acc[1] + (float)sv[1]) * s + bv0.y;
    o0.z = (acc[2] + (float)sv[2]) * s + bv0.z;
    o0.w = (acc[3] + (float)sv[3]) * s + bv0.w;
    o1.x = (acc[4] + (float)sv[4]) * s + bv1.x;
    o1.y = (acc[5] + (float)sv[5]) * s + bv1.y;
    o1.z = (acc[6] + (float)sv[6]) * s + bv1.z;
    o1.w = (acc[7] + (float)sv[7]) * s + bv1.w;
    float4* op = reinterpret_cast<float4*>(out + (size_t)node * 64 + coff);
    op[0] = o0;
    op[1] = o1;
  }
}

extern "C" void kernel_launch(void* const* d_in, const int* in_sizes, int n_in,
                              void* d_out, int out_size, void* d_ws, size_t ws_size,
                              hipStream_t stream) {
  const float* x  = (const float*)d_in[0];
  const int*   ei = (const int*)d_in[1];  // [2, NE] row-major
  const int* rows = ei;
  const int* cols = ei + NE;
  const float* W1 = (const float*)d_in[3];
  const float* b1 = (const float*)d_in[4];
  const float* W2 = (const float*)d_in[5];
  const float* b2 = (const float*)d_in[6];
  float* out = (float*)d_out;

  char* base = (char*)d_ws;
  constexpr size_t MB = 1 << 20;
  int*      deg       = (int*)(base + 0 * MB);
  int*      rowptr    = (int*)(base + 1 * MB);
  float*    dinv      = (float*)(base + 2 * MB);
  int*      btot      = (int*)(base + 3 * MB);
  int*      bucketBase= (int*)(base + 3 * MB + 16 * 1024);
  __half*   Wt1       = (__half*)(base + 3 * MB + 64 * 1024);
  __half*   Wt2       = (__half*)(base + 3 * MB + 128 * 1024);
  int*      table     = (int*)(base + 4 * MB);   // 800*784*4 = 2.5 MB
  int*      startOff  = (int*)(base + 7 * MB);   // 2.5 MB
  unsigned* binned    = (unsigned*)(base + 10 * MB);   // 6.4 MB
  int*      srcIdx    = (int*)(base + 17 * MB);        // 6.4 MB
  __half*   y         = (__half*)(base + 24 * MB);     // 25.6 MB
  __half*   z         = (__half*)(base + 50 * MB);     // 12.8 MB

  k_histwt<<<NBLK + 96, 256, 0, stream>>>(cols, table, W1, W2, Wt1, Wt2);
  k_scanT<<<NB, 256, 0, stream>>>(table, startOff, btot);
  k_scatB<<<NBLK, 256, 0, stream>>>(rows, cols, startOff, btot, bucketBase,
                                    binned);
  k_fillb<<<NB, 256, 0, stream>>>(binned, bucketBase, btot, rowptr, deg, dinv,
                                  srcIdx, (const float4*)x, (float2*)y);
  k_fused<<<NN / 16, 256, 0, stream>>>(y, rowptr, deg, srcIdx, dinv,
                                       Wt1, b1, Wt2, z);
  k_gath2<<<(NN + 7) / 8, 256, 0, stream>>>(z, rowptr, deg, srcIdx, dinv, b2, out);
}

// Round 13
// 283.524 us; speedup vs baseline: 1.0174x; 1.0174x over previous
//
#include <hip/hip_runtime.h>
#include <hip/hip_fp16.h>

// GCN 2-layer, CSR-gather, fp16 storage / fp32 math, MFMA GEMMs. R13.
// R12 lesson: NBLK 800 fragmented the binned scatter (2.5 edges/bucket/block
// = 10B per 64B line, cross-XCD ping-pong) -> reverted to 256. gath2
// half-wave gained nothing (same 8 rows/load-instr). R13 = R11 verbatim +
// the R11-PROVEN cross-node pipeline applied to k_gath2: 2 nodes per wave
// sequentially, headers preloaded by lanes 0-1, node i+1's first srcIdx
// chunk prefetched under node i's accumulate, self-row hoisted.
//   k_histwt : edge histogram (256 blks) || weight transpose (96 blks)
//   k_scanT  : column scan -> startOff, btot
//   k_scatB  : redundant LDS scan of btot + edge scatter (blk0 publishes)
//   k_fillb  : deg/rowptr/dinv + srcIdx + y=half(x*dinv)
//   k_fused  : R11 pipelined gather + GEMM1(relu,b1)+GEMM2(*dinv) [UNCHANGED]
//   k_gath2  : layer-2 gather, 2 nodes/wave pipelined -> out
// 6 dispatches, no global atomics, no device barriers.

constexpr int NN = 100000;
constexpr int NE = 1600000;
constexpr int BSH = 7;
constexpr int NB = (NN + 127) >> BSH;   // 782
constexpr int NBLK = 256;
constexpr int EPB = NE / NBLK;          // 6250
constexpr int TSTR = 784;

typedef _Float16 f16x8 __attribute__((ext_vector_type(8)));
typedef float f32x4 __attribute__((ext_vector_type(4)));

// ---- histogram (blocks 0..255) + weight transpose (blocks 256..351) ----
__global__ __launch_bounds__(256) void k_histwt(const int* __restrict__ cols,
                                                int* __restrict__ table,
                                                const float* __restrict__ W1,
                                                const float* __restrict__ W2,
                                                __half* __restrict__ Wt1,
                                                __half* __restrict__ Wt2) {
  if (blockIdx.x < NBLK) {
    __shared__ int cnt[NB];
    for (int i = threadIdx.x; i < NB; i += 256) cnt[i] = 0;
    __syncthreads();
    int base = blockIdx.x * EPB;
    for (int i = threadIdx.x; i < EPB; i += 256)
      atomicAdd(&cnt[cols[base + i] >> BSH], 1);
    __syncthreads();
    for (int i = threadIdx.x; i < NB; i += 256)
      table[blockIdx.x * TSTR + i] = cnt[i];
  } else {
    int i = (blockIdx.x - NBLK) * 256 + threadIdx.x;  // 24576 = 16384 + 8192
    if (i < 16384) {
      int k = i >> 7, n = i & 127;
      Wt1[n * 128 + k] = __float2half(W1[i]);
    } else {
      int j = i - 16384;
      int k = j >> 6, n = j & 63;
      Wt2[n * 128 + k] = __float2half(W2[j]);
    }
  }
}

// ------- scan table columns over blocks: startOff + bucket totals ------------
__global__ __launch_bounds__(256) void k_scanT(const int* __restrict__ table,
                                               int* __restrict__ startOff,
                                               int* __restrict__ btot) {
  __shared__ int s[256];
  int b = blockIdx.x, t = threadIdx.x;
  int v = table[t * TSTR + b];
  s[t] = v;
  __syncthreads();
  for (int off = 1; off < 256; off <<= 1) {
    int tmp = (t >= off) ? s[t - off] : 0;
    __syncthreads();
    s[t] += tmp;
    __syncthreads();
  }
  startOff[t * TSTR + b] = s[t] - v;
  if (t == 255) btot[b] = s[t];
}

// ---- per-block LDS scan of btot (redundant, proven) + edge scatter ----------
__global__ __launch_bounds__(256) void k_scatB(const int* __restrict__ rows,
                                               const int* __restrict__ cols,
                                               const int* __restrict__ startOff,
                                               const int* __restrict__ btot,
                                               int* __restrict__ bucketBase,
                                               unsigned* __restrict__ binned) {
  __shared__ int bb[NB];
  __shared__ int s[256];
  __shared__ int scnt[NB];
  int tid = threadIdx.x;
  int base4 = tid * 4;
  int d0 = (base4 + 0 < NB) ? btot[base4 + 0] : 0;
  int d1 = (base4 + 1 < NB) ? btot[base4 + 1] : 0;
  int d2 = (base4 + 2 < NB) ? btot[base4 + 2] : 0;
  int d3 = (base4 + 3 < NB) ? btot[base4 + 3] : 0;
  int tsum = d0 + d1 + d2 + d3;
  s[tid] = tsum;
  __syncthreads();
  for (int off = 1; off < 256; off <<= 1) {
    int tmp = (tid >= off) ? s[tid - off] : 0;
    __syncthreads();
    s[tid] += tmp;
    __syncthreads();
  }
  int ex = s[tid] - tsum;
  if (base4 + 0 < NB) bb[base4 + 0] = ex;
  if (base4 + 1 < NB) bb[base4 + 1] = ex + d0;
  if (base4 + 2 < NB) bb[base4 + 2] = ex + d0 + d1;
  if (base4 + 3 < NB) bb[base4 + 3] = ex + d0 + d1 + d2;
  __syncthreads();
  if (blockIdx.x == 0)
    for (int i = tid; i < NB; i += 256) bucketBase[i] = bb[i];
  for (int i = tid; i < NB; i += 256)
    scnt[i] = bb[i] + startOff[blockIdx.x * TSTR + i];
  __syncthreads();
  int base = blockIdx.x * EPB;
  for (int i = tid; i < EPB; i += 256) {
    int c = cols[base + i];
    int r = rows[base + i];
    int pos = atomicAdd(&scnt[c >> BSH], 1);
    binned[pos] = ((unsigned)r << BSH) | (unsigned)(c & 127);
  }
}

// ------- per-bucket fill: deg/rowptr/dinv + node-grouped srcIdx + y ----------
__global__ __launch_bounds__(256) void k_fillb(const unsigned* __restrict__ binned,
                                               const int* __restrict__ bucketBase,
                                               const int* __restrict__ btot,
                                               int* __restrict__ rowptr,
                                               int* __restrict__ deg,
                                               float* __restrict__ dinv,
                                               int* __restrict__ srcIdx,
                                               const float4* __restrict__ x4,
                                               float2* __restrict__ y8) {
  __shared__ int cnt[128];
  __shared__ int sc[128];
  __shared__ int rp[128];
  __shared__ float sdv[128];
  int b = blockIdx.x;
  int nb0 = b << BSH;
  int nn = min(128, NN - nb0);
  int tid = threadIdx.x;
  if (tid < 128) cnt[tid] = 0;
  __syncthreads();
  int ebeg = bucketBase[b];
  int eend = ebeg + btot[b];
  for (int p = ebeg + tid; p < eend; p += 256)
    atomicAdd(&cnt[binned[p] & 127], 1);
  __syncthreads();
  int v = (tid < 128) ? cnt[tid] : 0;
  if (tid < 128) sc[tid] = v;
  __syncthreads();
  for (int off = 1; off < 128; off <<= 1) {
    int tmp = (tid < 128 && tid >= off) ? sc[tid - off] : 0;
    __syncthreads();
    if (tid < 128) sc[tid] += tmp;
    __syncthreads();
  }
  if (tid < 128) {
    int ex = sc[tid] - v;
    rp[tid] = ebeg + ex;
    float dv = rsqrtf((float)v + 1.0f);
    sdv[tid] = dv;
    if (tid < nn) {
      rowptr[nb0 + tid] = ebeg + ex;
      deg[nb0 + tid] = v;
      dinv[nb0 + tid] = dv;
    }
    cnt[tid] = 0;
  }
  __syncthreads();
  for (int p = ebeg + tid; p < eend; p += 256) {
    unsigned pk = binned[p];
    int cl = pk & 127;
    int local = atomicAdd(&cnt[cl], 1);
    srcIdx[rp[cl] + local] = (int)(pk >> BSH);
  }
  // fused k_y: this bucket's x rows -> y = half(x*dinv)
  int tot = nn << 5;
  const float4* xb = x4 + ((size_t)nb0 << 5);
  float2* yb = y8 + ((size_t)nb0 << 5);
  for (int i = tid; i < tot; i += 256) {
    float sfac = sdv[i >> 5];
    float4 vv = xb[i];
    union { __half2 h[2]; float2 f; } u;
    u.h[0] = __floats2half2_rn(vv.x * sfac, vv.y * sfac);
    u.h[1] = __floats2half2_rn(vv.z * sfac, vv.w * sfac);
    yb[i] = u.f;
  }
}

// ---- fused gather + GEMM1(+bias,relu) + GEMM2(+dinv), pipelined (R11) ------
__global__ __launch_bounds__(256, 8) void k_fused(
    const __half* __restrict__ y, const int* __restrict__ rowptr,
    const int* __restrict__ deg, const int* __restrict__ srcIdx,
    const float* __restrict__ dinv, const __half* __restrict__ Wt1,
    const float* __restrict__ b1, const __half* __restrict__ Wt2,
    __half* __restrict__ z) {
  __shared__ __align__(16) __half sA[16][136];
  __shared__ __align__(16) __half sB[16][136];
  const int w = threadIdx.x >> 6, l = threadIdx.x & 63;
  const int blk0 = blockIdx.x * 16;
  const int quad = l >> 4, m = l & 15;

  // header preload: lanes 0-3 hold deg/rowptr/dinv of the 4 nodes
  int hd = 0, hp = 0;
  float hv = 0.0f;
  if (l < 4) {
    hd = deg[blk0 + w * 4 + l];
    hp = rowptr[blk0 + w * 4 + l];
    hv = dinv[blk0 + w * 4 + l];
  }
  int d = __shfl(hd, 0);
  int ptr = __shfl(hp, 0);
  int my = (l < min(d, 64)) ? srcIdx[ptr + l] : 0;

  for (int i = 0; i < 4; ++i) {
    const int node = blk0 + w * 4 + i;
    const int dn = (i < 3) ? __shfl(hd, i + 1) : 0;
    const int pn = (i < 3) ? __shfl(hp, i + 1) : 0;
    int myn = (i < 3 && l < min(dn, 64)) ? srcIdx[pn + l] : 0;
    f16x8 sv = *reinterpret_cast<const f16x8*>(y + (size_t)node * 128 + m * 8);

    float acc[8];
#pragma unroll
    for (int j = 0; j < 8; j++) acc[j] = 0.0f;

    {
      int cnt = min(d, 64);
      int k = 0;
      for (; k + 16 <= cnt; k += 16) {
        int s0 = __shfl(my, k + quad);
        int s1 = __shfl(my, k + 4 + quad);
        int s2 = __shfl(my, k + 8 + quad);
        int s3 = __shfl(my, k + 12 + quad);
        f16x8 v0 = *reinterpret_cast<const f16x8*>(y + (size_t)s0 * 128 + m * 8);
        f16x8 v1 = *reinterpret_cast<const f16x8*>(y + (size_t)s1 * 128 + m * 8);
        f16x8 v2 = *reinterpret_cast<const f16x8*>(y + (size_t)s2 * 128 + m * 8);
        f16x8 v3 = *reinterpret_cast<const f16x8*>(y + (size_t)s3 * 128 + m * 8);
#pragma unroll
        for (int j = 0; j < 8; j++) acc[j] += (float)v0[j];
#pragma unroll
        for (int j = 0; j < 8; j++) acc[j] += (float)v1[j];
#pragma unroll
        for (int j = 0; j < 8; j++) acc[j] += (float)v2[j];
#pragma unroll
        for (int j = 0; j < 8; j++) acc[j] += (float)v3[j];
      }
      for (; k + 8 <= cnt; k += 8) {
        int s0 = __shfl(my, k + quad);
        int s1 = __shfl(my, k + 4 + quad);
        f16x8 v0 = *reinterpret_cast<const f16x8*>(y + (size_t)s0 * 128 + m * 8);
        f16x8 v1 = *reinterpret_cast<const f16x8*>(y + (size_t)s1 * 128 + m * 8);
#pragma unroll
        for (int j = 0; j < 8; j++) acc[j] += (float)v0[j];
#pragma unroll
        for (int j = 0; j < 8; j++) acc[j] += (float)v1[j];
      }
      for (; k < cnt; k += 4) {
        int idx = k + quad;
        bool valid = idx < cnt;
        int s0 = __shfl(my, valid ? idx : 0);
        f16x8 v0 = *reinterpret_cast<const f16x8*>(y + (size_t)s0 * 128 + m * 8);
        if (valid) {
#pragma unroll
          for (int j = 0; j < 8; j++) acc[j] += (float)v0[j];
        }
      }
    }
    for (int base = 64; base < d; base += 64) {  // rare tail d>64
      int cnt = min(64, d - base);
      int mt = (l < cnt) ? srcIdx[ptr + base + l] : 0;
      int k = 0;
      for (; k + 8 <= cnt; k += 8) {
        int s0 = __shfl(mt, k + quad);
        int s1 = __shfl(mt, k + 4 + quad);
        f16x8 v0 = *reinterpret_cast<const f16x8*>(y + (size_t)s0 * 128 + m * 8);
        f16x8 v1 = *reinterpret_cast<const f16x8*>(y + (size_t)s1 * 128 + m * 8);
#pragma unroll
        for (int j = 0; j < 8; j++) acc[j] += (float)v0[j];
#pragma unroll
        for (int j = 0; j < 8; j++) acc[j] += (float)v1[j];
      }
      for (; k < cnt; k += 4) {
        int idx = k + quad;
        bool valid = idx < cnt;
        int s0 = __shfl(mt, valid ? idx : 0);
        f16x8 v0 = *reinterpret_cast<const f16x8*>(y + (size_t)s0 * 128 + m * 8);
        if (valid) {
#pragma unroll
          for (int j = 0; j < 8; j++) acc[j] += (float)v0[j];
        }
      }
    }

#pragma unroll
    for (int j = 0; j < 8; j++) acc[j] += __shfl_xor(acc[j], 16);
#pragma unroll
    for (int j = 0; j < 8; j++) acc[j] += __shfl_xor(acc[j], 32);
    if (quad == 0) {
      float scn = __shfl(hv, i);
      f16x8 o;
#pragma unroll
      for (int j = 0; j < 8; j++)
        o[j] = (_Float16)((acc[j] + (float)sv[j]) * scn);
      *reinterpret_cast<f16x8*>(&sA[w * 4 + i][m * 8]) = o;
    }
    d = dn;
    ptr = pn;
    my = myn;
  }
  __syncthreads();

  // GEMM1: wave w -> col tiles 2w, 2w+1
  f16x8 afrag[4];
#pragma unroll
  for (int kk = 0; kk < 4; kk++)
    afrag[kk] = *reinterpret_cast<const f16x8*>(&sA[m][kk * 32 + quad * 8]);
  f32x4 acc1[2];
#pragma unroll
  for (int t = 0; t < 2; t++) {
    float bv = b1[(w * 2 + t) * 16 + m];
    acc1[t] = (f32x4){bv, bv, bv, bv};
  }
#pragma unroll
  for (int kk = 0; kk < 4; kk++) {
#pragma unroll
    for (int t = 0; t < 2; t++) {
      f16x8 b = *reinterpret_cast<const f16x8*>(
          Wt1 + (size_t)((w * 2 + t) * 16 + m) * 128 + kk * 32 + quad * 8);
      acc1[t] = __builtin_amdgcn_mfma_f32_16x16x32_f16(afrag[kk], b, acc1[t], 0, 0, 0);
    }
  }
#pragma unroll
  for (int t = 0; t < 2; t++)
#pragma unroll
    for (int i = 0; i < 4; i++)
      sB[quad * 4 + i][(w * 2 + t) * 16 + m] =
          __float2half(fmaxf(acc1[t][i], 0.0f));
  __syncthreads();

  // GEMM2: wave w -> col tile w
  f16x8 hfrag[4];
#pragma unroll
  for (int kk = 0; kk < 4; kk++)
    hfrag[kk] = *reinterpret_cast<const f16x8*>(&sB[m][kk * 32 + quad * 8]);
  f32x4 acc2 = (f32x4){0.f, 0.f, 0.f, 0.f};
#pragma unroll
  for (int kk = 0; kk < 4; kk++) {
    f16x8 b = *reinterpret_cast<const f16x8*>(
        Wt2 + (size_t)(w * 16 + m) * 128 + kk * 32 + quad * 8);
    acc2 = __builtin_amdgcn_mfma_f32_16x16x32_f16(hfrag[kk], b, acc2, 0, 0, 0);
  }
  float rs[4];
#pragma unroll
  for (int i = 0; i < 4; i++) rs[i] = dinv[blk0 + quad * 4 + i];
#pragma unroll
  for (int i = 0; i < 4; i++)
    sA[quad * 4 + i][w * 16 + m] = __float2half(acc2[i] * rs[i]);
  __syncthreads();

  if (threadIdx.x < 128) {
    int r = threadIdx.x >> 3, cc = threadIdx.x & 7;
    *reinterpret_cast<float4*>(z + (size_t)(blk0 + r) * 64 + cc * 8) =
        *reinterpret_cast<const float4*>(&sA[r][cc * 8]);
  }
}

// ---- layer-2 gather, 2 nodes per wave SEQUENTIALLY, R11-style pipeline ------
// Full wave per node (8 slots g x 8 chunks c, proven R11 inner loop, 4-deep).
// Lanes 0-1 preload both node headers; node i+1's first srcIdx chunk is
// issued before node i's accumulate; self-row load hoisted. Grid NN/8=12500.
__global__ __launch_bounds__(256) void k_gath2(const __half* __restrict__ z,
                                               const int* __restrict__ rowptr,
                                               const int* __restrict__ deg,
                                               const int* __restrict__ srcIdx,
                                               const float* __restrict__ dinv,
                                               const float* __restrict__ b2,
                                               float* __restrict__ out) {
  const int lane = threadIdx.x & 63;
  const int g = lane >> 3;       // neighbor slot 0..7
  const int c = lane & 7;        // column chunk: halfs [c*8, c*8+8)
  const size_t coff = (size_t)c * 8;
  const int nb = blockIdx.x * 8 + ((threadIdx.x >> 6) << 1);  // first node

  // header preload: lanes 0-1 hold deg/rowptr/dinv of the 2 nodes
  int hd = 0, hp = 0;
  float hv = 0.0f;
  if (lane < 2) {
    hd = deg[nb + lane];
    hp = rowptr[nb + lane];
    hv = dinv[nb + lane];
  }
  int d = __shfl(hd, 0);
  int p = __shfl(hp, 0);
  int my = (lane < min(d, 64)) ? srcIdx[p + lane] : 0;

  for (int i = 0; i < 2; ++i) {
    const int node = nb + i;
    const int dn = (i < 1) ? __shfl(hd, 1) : 0;
    const int pn = (i < 1) ? __shfl(hp, 1) : 0;
    int myn = (i < 1 && lane < min(dn, 64)) ? srcIdx[pn + lane] : 0;
    f16x8 sv = *reinterpret_cast<const f16x8*>(z + (size_t)node * 64 + coff);

    float acc[8];
#pragma unroll
    for (int j = 0; j < 8; j++) acc[j] = 0.0f;

    // ---- fast path: chunk 0 (d<=64 covers ~100% of Poisson(16) nodes) ----
    {
      int cnt = min(d, 64);
      int k = 0;
      for (; k + 32 <= cnt; k += 32) {   // 32 neighbors, 4 loads in flight
        int s0 = __shfl(my, k + g);
        int s1 = __shfl(my, k + 8 + g);
        int s2 = __shfl(my, k + 16 + g);
        int s3 = __shfl(my, k + 24 + g);
        f16x8 v0 = *reinterpret_cast<const f16x8*>(z + (size_t)s0 * 64 + coff);
        f16x8 v1 = *reinterpret_cast<const f16x8*>(z + (size_t)s1 * 64 + coff);
        f16x8 v2 = *reinterpret_cast<const f16x8*>(z + (size_t)s2 * 64 + coff);
        f16x8 v3 = *reinterpret_cast<const f16x8*>(z + (size_t)s3 * 64 + coff);
#pragma unroll
        for (int j = 0; j < 8; j++) acc[j] += (float)v0[j];
#pragma unroll
        for (int j = 0; j < 8; j++) acc[j] += (float)v1[j];
#pragma unroll
        for (int j = 0; j < 8; j++) acc[j] += (float)v2[j];
#pragma unroll
        for (int j = 0; j < 8; j++) acc[j] += (float)v3[j];
      }
      for (; k + 16 <= cnt; k += 16) {   // 16 neighbors, 2 loads in flight
        int s0 = __shfl(my, k + g);
        int s1 = __shfl(my, k + 8 + g);
        f16x8 v0 = *reinterpret_cast<const f16x8*>(z + (size_t)s0 * 64 + coff);
        f16x8 v1 = *reinterpret_cast<const f16x8*>(z + (size_t)s1 * 64 + coff);
#pragma unroll
        for (int j = 0; j < 8; j++) acc[j] += (float)v0[j];
#pragma unroll
        for (int j = 0; j < 8; j++) acc[j] += (float)v1[j];
      }
      for (; k < cnt; k += 8) {          // remainder, predicated
        int idx = k + g;
        bool valid = idx < cnt;
        int s0 = __shfl(my, valid ? idx : 0);
        f16x8 v0 = *reinterpret_cast<const f16x8*>(z + (size_t)s0 * 64 + coff);
        if (valid) {
#pragma unroll
          for (int j = 0; j < 8; j++) acc[j] += (float)v0[j];
        }
      }
    }
    // ---- rare tail: d > 64 ----
    for (int base = 64; base < d; base += 64) {
      int cnt = min(64, d - base);
      int mt = (lane < cnt) ? srcIdx[p + base + lane] : 0;
      int k = 0;
      for (; k + 16 <= cnt; k += 16) {
        int s0 = __shfl(mt, k + g);
        int s1 = __shfl(mt, k + 8 + g);
        f16x8 v0 = *reinterpret_cast<const f16x8*>(z + (size_t)s0 * 64 + coff);
        f16x8 v1 = *reinterpret_cast<const f16x8*>(z + (size_t)s1 * 64 + coff);
#pragma unroll
        for (int j = 0; j < 8; j++) acc[j] += (float)v0[j];
#pragma unroll
        for (int j = 0; j < 8; j++) acc[j] += (float)v1[j];
      }
      for (; k < cnt; k += 8) {
        int idx = k + g;
        bool valid = idx < cnt;
        int s0 = __shfl(mt, valid ? idx : 0);
        f16x8 v0 = *reinterpret_cast<const f16x8*>(z + (size_t)s0 * 64 + coff);
        if (valid) {
#pragma unroll
          for (int j = 0; j < 8; j++) acc[j] += (float)v0[j];
        }
      }
    }

#pragma unroll
    for (int j = 0; j < 8; j++) acc[j] += __shfl_xor(acc[j], 8);
#pragma unroll
    for (int j = 0; j < 8; j++) acc[j] += __shfl_xor(acc[j], 16);
#pragma unroll
    for (int j = 0; j < 8; j++) acc[j] += __shfl_xor(acc[j], 32);
    if (g == 0) {
      float s = __shfl(hv, i);
      const float4* b4 = reinterpret_cast<const float4*>(b2);
      float4 bv0 = b4[2 * c], bv1 = b4[2 * c + 1];
      float4 o0, o1;
      o0.x = (acc[0] + (float)sv[0]) * s + bv0.x;
      o0.y = (acc[1] + (float)sv[1]) * s + bv0.y;
      o0.z = (acc[2] + (float)sv[2]) * s + bv0.z;
      o0.w = (acc[3] + (float)sv[3]) * s + bv0.w;
      o1.x = (acc[4] + (float)sv[4]) * s + bv1.x;
      o1.y = (acc[5] + (float)sv[5]) * s + bv1.y;
      o1.z = (acc[6] + (float)sv[6]) * s + bv1.z;
      o1.w = (acc[7] + (float)sv[7]) * s + bv1.w;
      float4* op = reinterpret_cast<float4*>(out + (size_t)node * 64 + coff);
      op[0] = o0;
      op[1] = o1;
    }
    d = dn;
    p = pn;
    my = myn;
  }
}

extern "C" void kernel_launch(void* const* d_in, const int* in_sizes, int n_in,
                              void* d_out, int out_size, void* d_ws, size_t ws_size,
                              hipStream_t stream) {
  const float* x  = (const float*)d_in[0];
  const int*   ei = (const int*)d_in[1];  // [2, NE] row-major
  const int* rows = ei;
  const int* cols = ei + NE;
  const float* W1 = (const float*)d_in[3];
  const float* b1 = (const float*)d_in[4];
  const float* W2 = (const float*)d_in[5];
  const float* b2 = (const float*)d_in[6];
  float* out = (float*)d_out;

  char* base = (char*)d_ws;
  constexpr size_t MB = 1 << 20;
  int*      deg       = (int*)(base + 0 * MB);
  int*      rowptr    = (int*)(base + 1 * MB);
  float*    dinv      = (float*)(base + 2 * MB);
  int*      btot      = (int*)(base + 3 * MB);
  int*      bucketBase= (int*)(base + 3 * MB + 16 * 1024);
  __half*   Wt1       = (__half*)(base + 3 * MB + 64 * 1024);
  __half*   Wt2       = (__half*)(base + 3 * MB + 128 * 1024);
  int*      table     = (int*)(base + 4 * MB);
  int*      startOff  = (int*)(base + 5 * MB);
  unsigned* binned    = (unsigned*)(base + 6 * MB);
  int*      srcIdx    = (int*)(base + 13 * MB);
  __half*   y         = (__half*)(base + 20 * MB);    // 25.6 MB
  __half*   z         = (__half*)(base + 46 * MB);    // 12.8 MB

  k_histwt<<<NBLK + 96, 256, 0, stream>>>(cols, table, W1, W2, Wt1, Wt2);
  k_scanT<<<NB, 256, 0, stream>>>(table, startOff, btot);
  k_scatB<<<NBLK, 256, 0, stream>>>(rows, cols, startOff, btot, bucketBase,
                                    binned);
  k_fillb<<<NB, 256, 0, stream>>>(binned, bucketBase, btot, rowptr, deg, dinv,
                                  srcIdx, (const float4*)x, (float2*)y);
  k_fused<<<NN / 16, 256, 0, stream>>>(y, rowptr, deg, srcIdx, dinv,
                                       Wt1, b1, Wt2, z);
  k_gath2<<<NN / 8, 256, 0, stream>>>(z, rowptr, deg, srcIdx, dinv, b2, out);
}